// Round 11
// baseline (325.713 us; speedup 1.0000x reference)
//
#include <hip/hip_runtime.h>

typedef _Float16 half8 __attribute__((ext_vector_type(8)));
typedef _Float16 half4v __attribute__((ext_vector_type(4)));
typedef float f32x4 __attribute__((ext_vector_type(4)));

#define OFF_PRED 26214400      // 32*128*128*50
#define OFF_XU   56934400      // OFF_PRED + 32*64*300*50
#define NBP 8                  // bp per block; grid = 2048/NBP = 256 = 1 block/CU

// ---- K0: build M in MFMA-fragment order.
// Logical M[640][320]: rows 0..255 = C, 256..555 = A, rest 0; cols k<300 real, else 0.
// dst elem = ((mt*10 + ks)*64 + lane)*8 + e, m = mt*16 + (lane&15), k = ks*32 + (lane>>4)*8 + e.
__global__ void build_M(const float* __restrict__ A, const float* __restrict__ C,
                        _Float16* __restrict__ M) {
    int idx = blockIdx.x * 256 + threadIdx.x;
    if (idx >= 640 * 320) return;
    int e    = idx & 7;
    int lane = (idx >> 3) & 63;
    int fs   = idx >> 9;                        // mt*10 + ks
    int mt = fs / 10, ks = fs % 10;
    int m = mt * 16 + (lane & 15);
    int k = ks * 32 + (lane >> 4) * 8 + e;
    float v = 0.f;
    if (k < 300) {
        if (m < 256) v = C[m * 300 + k];
        else if (m < 556) v = A[(m - 256) * 300 + k];
    }
    M[idx] = (_Float16)v;
}

// ---- K1: persistent block per CU. 512 thr / 8 waves; wave g owns m-group g
//      (rows 80g..80g+80, 5 mt) x all 4 n-tiles (acc 5x4=80). NBP bp's sequential,
//      double-buffered LDS (2 x 40960 B = full 160 KB -> 1 block/CU).
//      Pipeline per it: compute(buf,bp) -> stageL(bp+1) -> epilogue(bp) -> stageW(buf^1) -> barrier.
//      512-thr block => reg cap 256/wave: acc+stage+bf fit without spill.
//      LDS tile: row n (ext-col) stride 640 B, swz: byte ^ ((row&7)<<4).
__global__ __launch_bounds__(512, 2) void gemm_main(
    const float* __restrict__ X, const float* __restrict__ x0,
    const _Float16* __restrict__ M, float* __restrict__ out)
{
    __shared__ _Float16 lds[2][64 * 320];       // 2 x 40960 B
    const int tid = threadIdx.x;
    const int wave = tid >> 6, lane = tid & 63;
    const int lr = lane & 15, lg = lane >> 4;
    const int g = wave;
    const int bp0 = blockIdx.x * NBP;

    // precomputed staging coords: item i = tid + u*512 -> (t = i%50, jq = i/50)
    int offg[8], offl[8];
    #pragma unroll
    for (int u = 0; u < 8; u++) {
        int i = tid + u * 512;
        int t = i % 50, jq = i / 50;
        offg[u] = jq * 200 + t;                 // float index into X_bp (j = jq*4)
        int row = t + 1;
        offl[u] = row * 640 + ((jq * 8) ^ ((row & 7) << 4));
    }
    const bool v7 = tid < 166;                  // item u=7 valid (3750 - 7*512 = 166)

    // B-frag base (fragment-ordered M): frag (mt=g*5+j, ks) = contiguous 1KB
    const _Float16* Mw = M + g * 50 * 512 + lane * 8;

    // zero-fill both buffers (pad cols 300..319 and rows 51..63 stay zero forever)
    {
        char* l0 = (char*)&lds[0][0];
        #pragma unroll
        for (int u = 0; u < 20; u++)
            *(unsigned long long*)(l0 + tid * 8 + u * 4096) = 0ULL;
    }
    __syncthreads();

    float sx[8][4], s0x[4];

#define STAGE_L(bp) { const float* Xb_ = X + (bp) * 15000;                          \
    _Pragma("unroll")                                                                \
    for (int u = 0; u < 8; u++) if (u < 7 || v7) {                                   \
        const float* s_ = Xb_ + offg[u];                                             \
        sx[u][0] = s_[0]; sx[u][1] = s_[50]; sx[u][2] = s_[100]; sx[u][3] = s_[150]; \
    }                                                                                \
    if (tid < 75) { f32x4 v_ = *(const f32x4*)(x0 + (bp) * 300 + tid * 4);           \
        s0x[0] = v_.x; s0x[1] = v_.y; s0x[2] = v_.z; s0x[3] = v_.w; } }

#define STAGE_W(wbc) { char* wb_ = (wbc);                                            \
    _Pragma("unroll")                                                                \
    for (int u = 0; u < 8; u++) if (u < 7 || v7) {                                   \
        half4v h4_ = {(_Float16)sx[u][0], (_Float16)sx[u][1],                        \
                      (_Float16)sx[u][2], (_Float16)sx[u][3]};                       \
        *(half4v*)(wb_ + offl[u]) = h4_;                                             \
    }                                                                                \
    if (tid < 75) { half4v h4_ = {(_Float16)s0x[0], (_Float16)s0x[1],                \
                                  (_Float16)s0x[2], (_Float16)s0x[3]};               \
        *(half4v*)(wb_ + tid * 8) = h4_; } }      /* row 0 swizzle = identity */

    // prologue: stage bp0 into buf 0
    STAGE_L(bp0);
    STAGE_W((char*)&lds[0][0]);
    __syncthreads();

    // A-frag: row = nt*16 + lr, byte = row*640 + ((ks*64 + lg*16) ^ ((row&7)<<4))
    #define LDSA(base, nt, ks) (*(const half8*)((base) + ((nt) * 16 + lr) * 640 + \
                               (((ks) * 64 + lg * 16) ^ ((lr & 7) << 4))))

    for (int it = 0; it < NBP; ++it) {
        const int bp = bp0 + it;
        const int b = bp >> 6, p = bp & 63;
        char* rb = (char*)&lds[it & 1][0];

        // ---- compute ----
        f32x4 acc[5][4];
        #pragma unroll
        for (int j = 0; j < 5; j++)
            #pragma unroll
            for (int nt = 0; nt < 4; nt++)
                acc[j][nt] = (f32x4){0.f, 0.f, 0.f, 0.f};

        #pragma unroll
        for (int ks = 0; ks < 10; ks++) {
            half8 bf0 = *(const half8*)(Mw + (0 * 10 + ks) * 512);
            half8 bf1 = *(const half8*)(Mw + (1 * 10 + ks) * 512);
            half8 bf2 = *(const half8*)(Mw + (2 * 10 + ks) * 512);
            half8 bf3 = *(const half8*)(Mw + (3 * 10 + ks) * 512);
            half8 bf4 = *(const half8*)(Mw + (4 * 10 + ks) * 512);
            #pragma unroll
            for (int nt = 0; nt < 4; nt++) {
                half8 a = LDSA(rb, nt, ks);
                acc[0][nt] = __builtin_amdgcn_mfma_f32_16x16x32_f16(a, bf0, acc[0][nt], 0, 0, 0);
                acc[1][nt] = __builtin_amdgcn_mfma_f32_16x16x32_f16(a, bf1, acc[1][nt], 0, 0, 0);
                acc[2][nt] = __builtin_amdgcn_mfma_f32_16x16x32_f16(a, bf2, acc[2][nt], 0, 0, 0);
                acc[3][nt] = __builtin_amdgcn_mfma_f32_16x16x32_f16(a, bf3, acc[3][nt], 0, 0, 0);
                acc[4][nt] = __builtin_amdgcn_mfma_f32_16x16x32_f16(a, bf4, acc[4][nt], 0, 0, 0);
            }
        }

        // ---- issue next bp's global loads; latency hides under epilogue stores ----
        if (it + 1 < NBP) STAGE_L(bp + 1);

        // ---- epilogue: col m = g*80 + j*16 + lr, ext-col n = nt*16 + lg*4 + q ----
        {
            const int gr = p >> 3, gc = p & 7;
            #pragma unroll
            for (int j = 0; j < 5; j++) {
                int colm = g * 80 + j * 16 + lr;
                if (colm < 256) {
                    // recon row d -> vid[b][gr*16 + d/16][gc*16 + d%16][t], t = n-1
                    int base = b * 819200 + ((gr * 16 + (colm >> 4)) * 128 + gc * 16 + (colm & 15)) * 50;
                    #pragma unroll
                    for (int nt = 0; nt < 4; nt++) {
                        int t0 = nt * 16 + lg * 4;
                        if (t0 == 0) {
                            out[base + 0] = acc[j][0][1];
                            out[base + 1] = acc[j][0][2];
                            out[base + 2] = acc[j][0][3];
                        } else if (t0 <= 46) {
                            f32x4 v = acc[j][nt];
                            __builtin_memcpy(&out[base + t0 - 1], &v, 16);
                        } else if (t0 == 48) {
                            out[base + 47] = acc[j][nt][0];
                            out[base + 48] = acc[j][nt][1];
                            out[base + 49] = acc[j][nt][2];
                        }
                    }
                } else if (colm < 556) {
                    // X_pred row i = colm-256, t = n
                    int base = OFF_PRED + (bp * 300 + (colm - 256)) * 50;
                    #pragma unroll
                    for (int nt = 0; nt < 4; nt++) {
                        int t0 = nt * 16 + lg * 4;
                        if (t0 <= 46) {
                            f32x4 v = acc[j][nt];
                            __builtin_memcpy(&out[base + t0], &v, 16);
                        } else if (t0 == 48) {
                            out[base + 48] = acc[j][nt][0];
                            out[base + 49] = acc[j][nt][1];
                        }
                    }
                }
            }
        }

        // ---- convert + write next bp's tile into the other buffer ----
        if (it + 1 < NBP) STAGE_W((char*)&lds[(it & 1) ^ 1][0]);
        __syncthreads();
    }
    #undef LDSA
}

// ---- K2: X_U[b,i,t] = 0.5*(1+exp(-(B·U)[b,i,t])) * sum_p |X[b,p,i,t]|
__global__ void xu_kernel(const float* __restrict__ X, const float* __restrict__ U,
                          const float* __restrict__ B, float* __restrict__ out) {
    int id = blockIdx.x * 256 + threadIdx.x;
    if (id >= 480000) return;
    int t = id % 50;
    int i = (id / 50) % 300;
    int b = id / 15000;
    const float* xp = X + b * 960000 + i * 50 + t;
    float s = 0.f;
    #pragma unroll 8
    for (int pp = 0; pp < 64; pp++) s += fabsf(xp[pp * 15000]);
    float bu = 0.f;
    const float* up = U + b * 2000 + t;
    const float* Bp = B + i * 40;
    #pragma unroll 8
    for (int q = 0; q < 40; q++) bu += Bp[q] * up[q * 50];
    out[OFF_XU + id] = 0.5f * (1.f + expf(-bu)) * s;
}

extern "C" void kernel_launch(void* const* d_in, const int* in_sizes, int n_in,
                              void* d_out, int out_size, void* d_ws, size_t ws_size,
                              hipStream_t stream) {
    const float* X  = (const float*)d_in[0];
    const float* U  = (const float*)d_in[1];
    const float* x0 = (const float*)d_in[2];
    const float* A  = (const float*)d_in[3];
    const float* B  = (const float*)d_in[4];
    const float* C  = (const float*)d_in[5];
    float* out = (float*)d_out;
    _Float16* M = (_Float16*)d_ws;      // 640*320*2 = 409,600 B (fragment-ordered)

    build_M<<<800, 256, 0, stream>>>(A, C, M);
    gemm_main<<<256, 512, 0, stream>>>(X, x0, M, out);
    xu_kernel<<<1875, 256, 0, stream>>>(X, U, B, out);
}